// Round 3
// baseline (268.635 us; speedup 1.0000x reference)
//
#include <hip/hip_runtime.h>

typedef unsigned short u16;
typedef __attribute__((ext_vector_type(8))) short bf16x8;
typedef __attribute__((ext_vector_type(4))) float f32x4;

#define B_DIM 4096
#define D_DIM 512
#define H_DIM 16

__device__ __forceinline__ u16 f2bf(float f) {
  union { float f; unsigned u; } x;
  x.f = f;
  unsigned r = x.u + 0x7FFFu + ((x.u >> 16) & 1u);
  return (u16)(r >> 16);
}

__global__ __launch_bounds__(256) void prep_kernel(const float* __restrict__ conf,
                                                   float* __restrict__ lam,
                                                   float* __restrict__ count) {
  int i = blockIdx.x * 256 + threadIdx.x;
  float l = 1.0f - conf[i];
  l = fminf(fmaxf(l, 0.0f), 1.0f);
  float m = (l > 0.3f) ? 1.0f : 0.0f;
  lam[i] = l * m;
  for (int off = 32; off > 0; off >>= 1) m += __shfl_down(m, off, 64);
  __shared__ float wsum[4];
  int lane = threadIdx.x & 63;
  int w = threadIdx.x >> 6;
  if (lane == 0) wsum[w] = m;
  __syncthreads();
  if (threadIdx.x == 0) atomicAdd(count, wsum[0] + wsum[1] + wsum[2] + wsum[3]);
}

// ---- one transpose kernel for all 6 jobs ----
struct TJob {
  const float* in;
  u16* out;
  const float* scale;  // scale[r] applied, may be null
  int rows, cols, tiles_x, tile_off;
};
struct TJobs { TJob j[6]; };

// out[c*rows + r] = f2bf(in[r*cols + c] * scale[r])
__global__ __launch_bounds__(256) void mega_transpose(TJobs J) {
  __shared__ float tile[32][33];
  int b = blockIdx.x;
  const float* in = nullptr; u16* out = nullptr; const float* scale = nullptr;
  int rows = 0, cols = 0, rel = 0, tiles_x = 1;
#pragma unroll
  for (int i = 0; i < 6; ++i) {
    int off = J.j[i].tile_off;
    int cnt = J.j[i].tiles_x * (J.j[i].rows / 32);
    if (b >= off && b < off + cnt) {
      in = J.j[i].in; out = J.j[i].out; scale = J.j[i].scale;
      rows = J.j[i].rows; cols = J.j[i].cols; tiles_x = J.j[i].tiles_x;
      rel = b - off;
    }
  }
  long long c0 = (long long)(rel % tiles_x) * 32;
  long long r0 = (long long)(rel / tiles_x) * 32;
  int tx = threadIdx.x & 31, ty = threadIdx.x >> 5;
#pragma unroll
  for (int i = 0; i < 4; ++i) {
    int row = ty + i * 8;
    float v = in[(r0 + row) * cols + c0 + tx];
    if (scale) v *= scale[r0 + row];
    tile[row][tx] = v;
  }
  __syncthreads();
#pragma unroll
  for (int i = 0; i < 4; ++i) {
    int orow = ty + i * 8;
    out[(c0 + orow) * rows + r0 + tx] = f2bf(tile[tx][orow]);
  }
}

// C(M,N) = alpha * A(M,K) @ Bt(N,K)^T ; operands row-major, k contiguous.
// AF32/BF32: operand stored as f32, converted to bf16 during LDS staging.
// mode 0: atomicAdd into f32 C (split-K; C pre-zeroed)
// mode 1: store bf16 (alpha applied)
// mode 2: store f32 * alpha
// mode 3: store f32 = addsrc + acc / (count + 1e-6)
#define LDT 72  // 64 + 8 bf16 pad (16B): only free 2-way bank aliasing on ds_read_b128
template <bool AF32, bool BF32>
__global__ __launch_bounds__(256) void gemm_bt(
    const void* __restrict__ Av, long long lda, long long sa_b,
    const void* __restrict__ Btv, long long ldb, long long sb_b,
    void* __restrict__ Cv, long long ldc, long long sc_b,
    const float* __restrict__ addsrc, long long sadd_b,
    const float* __restrict__ count_ptr,
    float alpha, int K, int k_chunk, int batched, int mode) {
  __shared__ u16 As[64 * LDT];
  __shared__ u16 Bs[64 * LDT];

  const int tid = threadIdx.x;
  const long long n0 = (long long)blockIdx.x * 64;
  const long long m0 = (long long)blockIdx.y * 64;
  const int bz = blockIdx.z;

  long long aoff = 0, boff = 0, coff = 0;
  long long k0 = 0;
  int Kl = K;
  if (batched) {
    aoff = (long long)bz * sa_b;
    boff = (long long)bz * sb_b;
    coff = (long long)bz * sc_b;
  } else {
    k0 = (long long)bz * k_chunk;
    Kl = k_chunk;
  }

  const int lr = tid >> 3;       // 0..31 tile row
  const int lc = (tid & 7) * 8;  // k offset in elements (8 bf16 = 16B)
  const int lane = tid & 63;
  const int wave = tid >> 6;
  const int wm = (wave & 1) * 32;
  const int wn = (wave >> 1) * 32;
  const int fm = lane & 15;
  const int fg = lane >> 4;

  f32x4 zero = {0.f, 0.f, 0.f, 0.f};
  f32x4 acc[2][2];
  acc[0][0] = zero; acc[0][1] = zero; acc[1][0] = zero; acc[1][1] = zero;

  for (int t = 0; t < Kl; t += 64) {
#pragma unroll
    for (int p = 0; p < 2; ++p) {
      int row = lr + p * 32;
      // A tile
      if (AF32) {
        const float* src = (const float*)Av + aoff + (m0 + row) * lda + k0 + t + lc;
        float4 v0 = *(const float4*)src;
        float4 v1 = *(const float4*)(src + 4);
        ushort4 o0 = {f2bf(v0.x), f2bf(v0.y), f2bf(v0.z), f2bf(v0.w)};
        ushort4 o1 = {f2bf(v1.x), f2bf(v1.y), f2bf(v1.z), f2bf(v1.w)};
        *(ushort4*)&As[row * LDT + lc] = o0;
        *(ushort4*)&As[row * LDT + lc + 4] = o1;
      } else {
        uint4 av = *(const uint4*)((const u16*)Av + aoff + (m0 + row) * lda + k0 + t + lc);
        *(uint4*)&As[row * LDT + lc] = av;
      }
      // B tile
      if (BF32) {
        const float* src = (const float*)Btv + boff + (n0 + row) * ldb + k0 + t + lc;
        float4 v0 = *(const float4*)src;
        float4 v1 = *(const float4*)(src + 4);
        ushort4 o0 = {f2bf(v0.x), f2bf(v0.y), f2bf(v0.z), f2bf(v0.w)};
        ushort4 o1 = {f2bf(v1.x), f2bf(v1.y), f2bf(v1.z), f2bf(v1.w)};
        *(ushort4*)&Bs[row * LDT + lc] = o0;
        *(ushort4*)&Bs[row * LDT + lc + 4] = o1;
      } else {
        uint4 bv = *(const uint4*)((const u16*)Btv + boff + (n0 + row) * ldb + k0 + t + lc);
        *(uint4*)&Bs[row * LDT + lc] = bv;
      }
    }
    __syncthreads();
#pragma unroll
    for (int kc = 0; kc < 64; kc += 32) {
      bf16x8 a0 = *(const bf16x8*)&As[(wm + fm) * LDT + kc + fg * 8];
      bf16x8 a1 = *(const bf16x8*)&As[(wm + 16 + fm) * LDT + kc + fg * 8];
      bf16x8 b0 = *(const bf16x8*)&Bs[(wn + fm) * LDT + kc + fg * 8];
      bf16x8 b1 = *(const bf16x8*)&Bs[(wn + 16 + fm) * LDT + kc + fg * 8];
      acc[0][0] = __builtin_amdgcn_mfma_f32_16x16x32_bf16(a0, b0, acc[0][0], 0, 0, 0);
      acc[0][1] = __builtin_amdgcn_mfma_f32_16x16x32_bf16(a0, b1, acc[0][1], 0, 0, 0);
      acc[1][0] = __builtin_amdgcn_mfma_f32_16x16x32_bf16(a1, b0, acc[1][0], 0, 0, 0);
      acc[1][1] = __builtin_amdgcn_mfma_f32_16x16x32_bf16(a1, b1, acc[1][1], 0, 0, 0);
    }
    __syncthreads();
  }

  float inv = 0.0f;
  if (mode == 3) inv = 1.0f / (*count_ptr + 1e-6f);
  const float* addb = addsrc ? (addsrc + (batched ? (long long)bz * sadd_b : 0)) : (const float*)0;

#pragma unroll
  for (int mi = 0; mi < 2; ++mi) {
#pragma unroll
    for (int r = 0; r < 4; ++r) {
      long long row = m0 + wm + mi * 16 + fg * 4 + r;
#pragma unroll
      for (int ni = 0; ni < 2; ++ni) {
        long long col = n0 + wn + ni * 16 + fm;
        long long hidx = row * ldc + col;
        float v = acc[mi][ni][r] * alpha;
        if (mode == 0) {
          atomicAdd((float*)Cv + coff + hidx, v);
        } else if (mode == 1) {
          ((u16*)Cv)[coff + hidx] = f2bf(v);
        } else if (mode == 2) {
          ((float*)Cv)[coff + hidx] = v;
        } else {
          ((float*)Cv)[coff + hidx] = addb[hidx] + acc[mi][ni][r] * inv;
        }
      }
    }
  }
}

extern "C" void kernel_launch(void* const* d_in, const int* in_sizes, int n_in,
                              void* d_out, int out_size, void* d_ws, size_t ws_size,
                              hipStream_t stream) {
  (void)in_sizes; (void)n_in; (void)out_size; (void)ws_size;
  const float* zq   = (const float*)d_in[0];
  const float* zs   = (const float*)d_in[1];
  const float* zv   = (const float*)d_in[2];
  const float* conf = (const float*)d_in[3];
  const float* Wk   = (const float*)d_in[4];
  const float* Wv   = (const float*)d_in[5];
  const float* Wo   = (const float*)d_in[6];
  const float* mem  = (const float*)d_in[7];

  float* vret = (float*)d_out;                      // (B, D)
  float* newmem = vret + (long long)B_DIM * D_DIM;  // (H, D, D)

  // workspace layout
  float* count = (float*)d_ws;                           // @0, 256 B
  float* Pf    = (float*)((char*)d_ws + 256);            // 1 MB f32
  float* Sf    = (float*)((char*)d_ws + 256 + 1048576);  // 1 MB f32
  float* lam   = (float*)((char*)d_ws + 2097408);        // 16 KB
  u16* bb      = (u16*)((char*)d_ws + 2113792);
  u16* zsT  = bb;              // 512 x 4096
  u16* zvlT = bb + 2097152;    // 512 x 4096 (lam-scaled)
  u16* WkT  = bb + 4194304;    // 8192 x 512  (= per-head Wk_h^T)
  u16* WvT  = bb + 8388608;    // 8192 x 512
  u16* memT = bb + 12582912;   // 512 x 8192
  u16* WoT  = bb + 16777216;   // 512 x 512
  u16* QT   = bb + 17039360;   // 512 x 512  (= Q^T, already /16)
  u16* UT   = bb + 17301504;   // 16 x 512 x 512 (= U_h^T)

  // zero count + Pf + Sf (split-K atomic targets)
  hipMemsetAsync(d_ws, 0, 2097408, stream);

  prep_kernel<<<B_DIM / 256, 256, 0, stream>>>(conf, lam, count);

  // all transposes in one dispatch
  TJobs J;
  J.j[0] = {zs,  zsT,  nullptr, 4096, 512, 16,  0};       // 2048 tiles
  J.j[1] = {zv,  zvlT, lam,     4096, 512, 16,  2048};    // 2048
  J.j[2] = {Wk,  WkT,  nullptr, 512, 8192, 256, 4096};    // 4096
  J.j[3] = {Wv,  WvT,  nullptr, 512, 8192, 256, 8192};    // 4096
  J.j[4] = {mem, memT, nullptr, 8192, 512, 16,  12288};   // 4096
  J.j[5] = {Wo,  WoT,  nullptr, 512, 512,  16,  16384};   // 256 -> total 16640
  mega_transpose<<<16640, 256, 0, stream>>>(J);

  // G1: Pf(512x512) = Wk(f32, 512x8192) @ Mflat  (Bt = memT), split-K 8, f32 atomics
  gemm_bt<true, false><<<dim3(8, 8, 8), 256, 0, stream>>>(
      Wk, 8192, 0, memT, 8192, 0, Pf, 512, 0,
      nullptr, 0, nullptr, 1.0f, 8192, 1024, 0, 0);

  // G2: QT = (1/16) * WoT @ P^T   (A = WoT bf16, Bt = Pf f32) -> bf16
  gemm_bt<false, true><<<dim3(8, 8, 1), 256, 0, stream>>>(
      WoT, 512, 0, Pf, 512, 0, QT, 512, 0,
      nullptr, 0, nullptr, 1.0f / 16.0f, 512, 512, 0, 1);

  // G3: vret = zq(f32) @ Q   (Bt = QT), f32 out
  gemm_bt<true, false><<<dim3(8, 64, 1), 256, 0, stream>>>(
      zq, 512, 0, QT, 512, 0, vret, 512, 0,
      nullptr, 0, nullptr, 1.0f, 512, 512, 0, 2);

  // G4: Sf = zs^T @ diag(lam) @ zv  (A = zsT, Bt = zvlT), split-K 4, f32 atomics
  gemm_bt<false, false><<<dim3(8, 8, 4), 256, 0, stream>>>(
      zsT, 4096, 0, zvlT, 4096, 0, Sf, 512, 0,
      nullptr, 0, nullptr, 1.0f, 4096, 1024, 0, 0);

  // G5: UT_h = (S @ Wv_h)^T  (A = WvT_h bf16, Bt = Sf f32), batched 16 heads -> bf16
  gemm_bt<false, true><<<dim3(8, 8, 16), 256, 0, stream>>>(
      WvT, 512, 262144, Sf, 512, 0, UT, 512, 262144,
      nullptr, 0, nullptr, 1.0f, 512, 512, 1, 1);

  // G6: newmem_h = mem_h + (Wk_h^T @ U_h) / (count+1e-6)  (A = WkT_h, Bt = UT_h)
  gemm_bt<false, false><<<dim3(8, 8, 16), 256, 0, stream>>>(
      WkT, 512, 262144, UT, 512, 262144, newmem, 512, 262144,
      mem, 262144, count, 1.0f, 512, 512, 1, 3);
}

// Round 4
// 232.961 us; speedup vs baseline: 1.1531x; 1.1531x over previous
//
#include <hip/hip_runtime.h>

typedef unsigned short u16;
typedef __attribute__((ext_vector_type(8))) short bf16x8;
typedef __attribute__((ext_vector_type(4))) float f32x4;

#define B_DIM 4096
#define D_DIM 512
#define H_DIM 16

typedef const __attribute__((address_space(1))) unsigned int* gas_t;
typedef __attribute__((address_space(3))) unsigned int* las_t;

__device__ __forceinline__ u16 f2bf(float f) {
  union { float f; unsigned u; } x;
  x.f = f;
  unsigned r = x.u + 0x7FFFu + ((x.u >> 16) & 1u);
  return (u16)(r >> 16);
}

__device__ __forceinline__ uint4 pack8(float4 v0, float4 v1) {
  union { uint4 q; u16 h[8]; } u;
  u.h[0] = f2bf(v0.x); u.h[1] = f2bf(v0.y); u.h[2] = f2bf(v0.z); u.h[3] = f2bf(v0.w);
  u.h[4] = f2bf(v1.x); u.h[5] = f2bf(v1.y); u.h[6] = f2bf(v1.z); u.h[7] = f2bf(v1.w);
  return u.q;
}

// ---- prep + transpose uber kernel ----
// kind 0: plain transpose f32->bf16; kind 1: transpose with lam(conf) row-scale;
// kind 2: count reduction (single block).
struct TJob {
  const float* in;
  u16* out;
  const float* conf;
  int rows, cols, tiles_x, tile_off, kind;
};
struct TJobs { TJob j[7]; };

__global__ __launch_bounds__(256) void mega_prep(TJobs J, float* __restrict__ countp) {
  __shared__ float tile[32][33];
  __shared__ float wsum[4];
  const int tid = threadIdx.x;
  int b = blockIdx.x;
  int sel = 0;
#pragma unroll
  for (int i = 1; i < 7; ++i)
    if (b >= J.j[i].tile_off) sel = i;
  TJob jb = J.j[sel];
  b -= jb.tile_off;

  if (jb.kind == 2) {
    float m = 0.f;
    for (int i = tid; i < B_DIM; i += 256) {
      float l = 1.0f - jb.in[i];
      l = fminf(fmaxf(l, 0.f), 1.f);
      m += (l > 0.3f) ? 1.f : 0.f;
    }
    for (int off = 32; off; off >>= 1) m += __shfl_down(m, off, 64);
    if ((tid & 63) == 0) wsum[tid >> 6] = m;
    __syncthreads();
    if (tid == 0) countp[0] = wsum[0] + wsum[1] + wsum[2] + wsum[3];
    return;
  }

  long long c0 = (long long)(b % jb.tiles_x) * 32;
  long long r0 = (long long)(b / jb.tiles_x) * 32;
  int tx = tid & 31, ty = tid >> 5;
#pragma unroll
  for (int i = 0; i < 4; ++i) {
    int row = ty + i * 8;
    float v = jb.in[(r0 + row) * jb.cols + c0 + tx];
    if (jb.kind == 1) {
      float l = 1.0f - jb.conf[r0 + row];
      l = fminf(fmaxf(l, 0.f), 1.f);
      v *= (l > 0.3f) ? l : 0.f;
    }
    tile[row][tx] = v;
  }
  __syncthreads();
#pragma unroll
  for (int i = 0; i < 4; ++i) {
    int orow = ty + i * 8;
    jb.out[(c0 + orow) * jb.rows + r0 + tx] = f2bf(tile[tx][orow]);
  }
}

// ---- uber GEMM: C(M,N) = alpha * A(M,K) @ Bt(N,K)^T ----
// 128x128 tile, BK=64, 4 waves each with 64x64 acc (4x4 16x16x32 frags).
// bf16 operands staged via global_load_lds (16B); f32 operands (aflag/bflag)
// staged via float4 load + convert + ds_write_b128.
// mode 0: atomicAdd f32 (split-K, C pre-zeroed); 1: store bf16*alpha;
// 2: store f32*alpha; 3: store f32 = addsrc + acc/(count+1e-6).
struct GJob {
  const void* A; const void* Bp; void* C;
  const float* addsrc; const float* cnt;
  long long lda, ldb, ldc, sa_b, sb_b, sc_b, sadd_b;
  float alpha;
  int K, k_chunk, tm, tn, nz, batched, mode, aflag, bflag, nblocks;
};
struct GJobs { GJob j[2]; };

__global__ __launch_bounds__(256) void gemm_uber(GJobs JJ) {
  __shared__ alignas(16) u16 As[128 * 64];
  __shared__ alignas(16) u16 Bs[128 * 64];

  int b = blockIdx.x;
  GJob J = JJ.j[0];
  if (b >= J.nblocks) { b -= J.nblocks; J = JJ.j[1]; }

  const int tilesper = J.tm * J.tn;
  const int bz = b / tilesper;
  const int rel = b % tilesper;
  const long long m0 = (long long)(rel / J.tn) * 128;
  const long long n0 = (long long)(rel % J.tn) * 128;

  long long aoff = 0, boff = 0, coff = 0, doff = 0, k0 = 0;
  int Kl = J.K;
  if (J.batched) {
    aoff = (long long)bz * J.sa_b;
    boff = (long long)bz * J.sb_b;
    coff = (long long)bz * J.sc_b;
    doff = (long long)bz * J.sadd_b;
  } else {
    k0 = (long long)bz * J.k_chunk;
    Kl = J.k_chunk;
  }

  const int tid = threadIdx.x;
  const int lane = tid & 63, wave = tid >> 6;
  const int wm = (wave & 1) * 64, wn = (wave >> 1) * 64;
  const int fm = lane & 15, fg = lane >> 4;

  f32x4 acc[4][4];
#pragma unroll
  for (int i = 0; i < 4; ++i)
#pragma unroll
    for (int j = 0; j < 4; ++j) acc[i][j] = (f32x4){0.f, 0.f, 0.f, 0.f};

  for (int t = 0; t < Kl; t += 64) {
    // ---- stage A ----
    if (!J.aflag) {
      const u16* Ab = (const u16*)J.A + aoff + k0 + t;
#pragma unroll
      for (int j = 0; j < 4; ++j) {
        int cc = wave * 4 + j;
        int row = cc * 8 + (lane >> 3);
        int k = (lane & 7) * 8;
        const u16* g = Ab + (m0 + row) * J.lda + k;
        __builtin_amdgcn_global_load_lds((gas_t)(const void*)g,
                                         (las_t)(void*)(As + cc * 512 + lane * 8),
                                         16, 0, 0);
      }
    } else {
      const float* Af = (const float*)J.A + aoff + k0 + t;
#pragma unroll
      for (int c = 0; c < 4; ++c) {
        int idx = c * 256 + tid;
        int row = idx >> 3, k8 = (idx & 7) * 8;
        const float* g = Af + (m0 + row) * J.lda + k8;
        float4 v0 = *(const float4*)g;
        float4 v1 = *(const float4*)(g + 4);
        *(uint4*)&As[row * 64 + k8] = pack8(v0, v1);
      }
    }
    // ---- stage B ----
    if (!J.bflag) {
      const u16* Bb = (const u16*)J.Bp + boff + k0 + t;
#pragma unroll
      for (int j = 0; j < 4; ++j) {
        int cc = wave * 4 + j;
        int row = cc * 8 + (lane >> 3);
        int k = (lane & 7) * 8;
        const u16* g = Bb + (n0 + row) * J.ldb + k;
        __builtin_amdgcn_global_load_lds((gas_t)(const void*)g,
                                         (las_t)(void*)(Bs + cc * 512 + lane * 8),
                                         16, 0, 0);
      }
    } else {
      const float* Bf = (const float*)J.Bp + boff + k0 + t;
#pragma unroll
      for (int c = 0; c < 4; ++c) {
        int idx = c * 256 + tid;
        int row = idx >> 3, k8 = (idx & 7) * 8;
        const float* g = Bf + (n0 + row) * J.ldb + k8;
        float4 v0 = *(const float4*)g;
        float4 v1 = *(const float4*)(g + 4);
        *(uint4*)&Bs[row * 64 + k8] = pack8(v0, v1);
      }
    }
    __syncthreads();
#pragma unroll
    for (int kc = 0; kc < 64; kc += 32) {
      bf16x8 af[4], bfr[4];
#pragma unroll
      for (int fi = 0; fi < 4; ++fi)
        af[fi] = *(const bf16x8*)&As[(wm + fi * 16 + fm) * 64 + kc + fg * 8];
#pragma unroll
      for (int fj = 0; fj < 4; ++fj)
        bfr[fj] = *(const bf16x8*)&Bs[(wn + fj * 16 + fm) * 64 + kc + fg * 8];
#pragma unroll
      for (int fi = 0; fi < 4; ++fi)
#pragma unroll
        for (int fj = 0; fj < 4; ++fj)
          acc[fi][fj] = __builtin_amdgcn_mfma_f32_16x16x32_bf16(af[fi], bfr[fj], acc[fi][fj], 0, 0, 0);
    }
    __syncthreads();
  }

  float inv = (J.mode == 3) ? 1.0f / (*J.cnt + 1e-6f) : 0.0f;
#pragma unroll
  for (int fi = 0; fi < 4; ++fi) {
#pragma unroll
    for (int r = 0; r < 4; ++r) {
      long long row = m0 + wm + fi * 16 + fg * 4 + r;
#pragma unroll
      for (int fj = 0; fj < 4; ++fj) {
        long long col = n0 + wn + fj * 16 + fm;
        long long idx = row * J.ldc + col;
        float v = acc[fi][fj][r];
        if (J.mode == 0) {
          atomicAdd((float*)J.C + idx, v * J.alpha);
        } else if (J.mode == 1) {
          ((u16*)J.C)[coff + idx] = f2bf(v * J.alpha);
        } else if (J.mode == 2) {
          ((float*)J.C)[coff + idx] = v * J.alpha;
        } else {
          ((float*)J.C)[coff + idx] = J.addsrc[doff + idx] + v * inv;
        }
      }
    }
  }
}

extern "C" void kernel_launch(void* const* d_in, const int* in_sizes, int n_in,
                              void* d_out, int out_size, void* d_ws, size_t ws_size,
                              hipStream_t stream) {
  (void)in_sizes; (void)n_in; (void)out_size; (void)ws_size;
  const float* zq   = (const float*)d_in[0];
  const float* zs   = (const float*)d_in[1];
  const float* zv   = (const float*)d_in[2];
  const float* conf = (const float*)d_in[3];
  const float* Wk   = (const float*)d_in[4];
  const float* Wv   = (const float*)d_in[5];
  const float* Wo   = (const float*)d_in[6];
  const float* mem  = (const float*)d_in[7];

  float* vret = (float*)d_out;                      // (B, D)
  float* newmem = vret + (long long)B_DIM * D_DIM;  // (H, D, D)

  // workspace: [count 256B][Pf 1MB][Sf 1MB][bf16 buffers]
  float* count = (float*)d_ws;
  float* Pf = (float*)((char*)d_ws + 256);
  float* Sf = (float*)((char*)d_ws + 256 + 1048576);
  u16* bb   = (u16*)((char*)d_ws + 2097408);
  u16* zsT  = bb;               // 512 x 4096
  u16* zvlT = bb + 2097152;     // 512 x 4096 (lam-scaled)
  u16* WkT  = bb + 4194304;     // 8192 x 512
  u16* WvT  = bb + 8388608;     // 8192 x 512
  u16* memT = bb + 12582912;    // 512 x 8192
  u16* WoT  = bb + 16777216;    // 512 x 512
  u16* QT   = bb + 17039360;    // 512 x 512 (Q^T, /16 folded)
  u16* UT   = bb + 17301504;    // 16 x 512 x 512 (U_h^T)

  hipMemsetAsync(d_ws, 0, 2097408, stream);  // count + Pf + Sf

  // D1: transposes + count
  TJobs T;
  T.j[0] = {zs,   zsT,  nullptr, 4096, 512,  16,  0,     0};
  T.j[1] = {zv,   zvlT, conf,    4096, 512,  16,  2048,  1};
  T.j[2] = {Wk,   WkT,  nullptr, 512,  8192, 256, 4096,  0};
  T.j[3] = {Wv,   WvT,  nullptr, 512,  8192, 256, 8192,  0};
  T.j[4] = {mem,  memT, nullptr, 8192, 512,  16,  12288, 0};
  T.j[5] = {Wo,   WoT,  nullptr, 512,  512,  16,  16384, 0};
  T.j[6] = {conf, nullptr, nullptr, 0, 0,    1,   16640, 2};
  mega_prep<<<16641, 256, 0, stream>>>(T, count);

  // D2: G1 (Pf = Wk @ memT^T, split-K 8) + G4 (Sf = zsT @ zvlT^T, split-K 8)
  GJobs D2;
  D2.j[0] = {Wk, memT, Pf, nullptr, nullptr,
             8192, 8192, 512, 0, 0, 0, 0,
             1.0f, 8192, 1024, 4, 4, 8, 0, 0, 1, 0, 128};
  D2.j[1] = {zsT, zvlT, Sf, nullptr, nullptr,
             4096, 4096, 512, 0, 0, 0, 0,
             1.0f, 4096, 512, 4, 4, 8, 0, 0, 0, 0, 128};
  gemm_uber<<<256, 256, 0, stream>>>(D2);

  // D3: G5 (UT_h = WvT_h @ Sf^T, batched 16) + G2 (QT = WoT @ Pf^T, /16)
  GJobs D3;
  D3.j[0] = {WvT, Sf, UT, nullptr, nullptr,
             512, 512, 512, 262144, 0, 262144, 0,
             1.0f, 512, 512, 4, 4, 16, 1, 1, 0, 1, 256};
  D3.j[1] = {WoT, Pf, QT, nullptr, nullptr,
             512, 512, 512, 0, 0, 0, 0,
             1.0f / 16.0f, 512, 512, 4, 4, 1, 0, 1, 0, 1, 16};
  gemm_uber<<<272, 256, 0, stream>>>(D3);

  // D4: G6 (newmem = mem + WkT_h @ UT_h^T / count, batched 16) + G3 (vret = zq @ QT^T)
  GJobs D4;
  D4.j[0] = {WkT, UT, newmem, mem, count,
             512, 512, 512, 262144, 262144, 262144, 262144,
             1.0f, 512, 512, 4, 4, 16, 1, 3, 0, 0, 256};
  D4.j[1] = {zq, QT, vret, nullptr, nullptr,
             512, 512, 512, 0, 0, 0, 0,
             1.0f, 512, 512, 32, 4, 1, 0, 2, 1, 0, 128};
  gemm_uber<<<384, 256, 0, stream>>>(D4);
}

// Round 5
// 218.388 us; speedup vs baseline: 1.2301x; 1.0667x over previous
//
#include <hip/hip_runtime.h>

typedef unsigned short u16;
typedef __attribute__((ext_vector_type(8))) short bf16x8;
typedef __attribute__((ext_vector_type(4))) float f32x4;

#define B_DIM 4096
#define D_DIM 512
#define H_DIM 16

typedef const __attribute__((address_space(1))) unsigned int* gas_t;
typedef __attribute__((address_space(3))) unsigned int* las_t;

__device__ __forceinline__ u16 f2bf(float f) {
  union { float f; unsigned u; } x;
  x.f = f;
  unsigned r = x.u + 0x7FFFu + ((x.u >> 16) & 1u);
  return (u16)(r >> 16);
}

__device__ __forceinline__ uint4 pack8(float4 v0, float4 v1) {
  union { uint4 q; u16 h[8]; } u;
  u.h[0] = f2bf(v0.x); u.h[1] = f2bf(v0.y); u.h[2] = f2bf(v0.z); u.h[3] = f2bf(v0.w);
  u.h[4] = f2bf(v1.x); u.h[5] = f2bf(v1.y); u.h[6] = f2bf(v1.z); u.h[7] = f2bf(v1.w);
  return u.q;
}

// ---- prep uber kernel ----
// kind 0: transpose f32->bf16; 1: transpose with lam(conf) row-scale;
// 2: count reduction (1 block); 3: linear convert f32->bf16 (2048 elems/block);
// 4: zero f32 (4096 floats/block).
struct TJob {
  const float* in;
  void* out;
  const float* conf;
  int rows, cols, tiles_x, tile_off, kind;
};
struct TJobs { TJob j[10]; };

__global__ __launch_bounds__(256) void mega_prep(TJobs J, float* __restrict__ countp) {
  __shared__ float tile[32][33];
  __shared__ float wsum[4];
  const int tid = threadIdx.x;
  int b = blockIdx.x;
  int sel = 0;
#pragma unroll
  for (int i = 1; i < 10; ++i)
    if (b >= J.j[i].tile_off) sel = i;
  TJob jb = J.j[sel];
  b -= jb.tile_off;

  if (jb.kind == 3) {  // linear convert
    long long base = (long long)b * 2048 + tid * 8;
    float4 v0 = *(const float4*)(jb.in + base);
    float4 v1 = *(const float4*)(jb.in + base + 4);
    *(uint4*)((u16*)jb.out + base) = pack8(v0, v1);
    return;
  }
  if (jb.kind == 4) {  // zero f32
    long long base = (long long)b * 4096 + tid * 16;
    float4 z = {0.f, 0.f, 0.f, 0.f};
    float* o = (float*)jb.out + base;
    *(float4*)o = z; *(float4*)(o + 4) = z; *(float4*)(o + 8) = z; *(float4*)(o + 12) = z;
    return;
  }
  if (jb.kind == 2) {  // count
    float m = 0.f;
    for (int i = tid; i < B_DIM; i += 256) {
      float l = 1.0f - jb.in[i];
      l = fminf(fmaxf(l, 0.f), 1.f);
      m += (l > 0.3f) ? 1.f : 0.f;
    }
    for (int off = 32; off; off >>= 1) m += __shfl_down(m, off, 64);
    if ((tid & 63) == 0) wsum[tid >> 6] = m;
    __syncthreads();
    if (tid == 0) countp[0] = wsum[0] + wsum[1] + wsum[2] + wsum[3];
    return;
  }

  // transpose kinds 0/1
  long long c0 = (long long)(b % jb.tiles_x) * 32;
  long long r0 = (long long)(b / jb.tiles_x) * 32;
  int tx = tid & 31, ty = tid >> 5;
#pragma unroll
  for (int i = 0; i < 4; ++i) {
    int row = ty + i * 8;
    float v = jb.in[(r0 + row) * jb.cols + c0 + tx];
    if (jb.kind == 1) {
      float l = 1.0f - jb.conf[r0 + row];
      l = fminf(fmaxf(l, 0.f), 1.f);
      v *= (l > 0.3f) ? l : 0.f;
    }
    tile[row][tx] = v;
  }
  __syncthreads();
#pragma unroll
  for (int i = 0; i < 4; ++i) {
    int orow = ty + i * 8;
    ((u16*)jb.out)[(c0 + orow) * jb.rows + r0 + tx] = f2bf(tile[tx][orow]);
  }
}

// ---- 64x64-tile GEMM, double-buffered, swizzled LDS ----
// C(M,N) = alpha * A(M,K) @ Bt(N,K)^T, both k-contiguous. 4 waves, each 32x32.
// bf16 operands via global_load_lds(16B); f32 (aflag/bflag) via float4+pack+ds_write.
// LDS chunk swizzle: LDS[row][cl] holds G[row][cl ^ (row&7)] (chunks of 8 elems).
// mode 0: atomicAdd f32 (split-K); 1: store bf16*alpha; 2: store f32*alpha;
// 3: store f32 = addsrc + acc/(count+1e-6).
struct GJob {
  const void* A; const void* Bp; void* C;
  const float* addsrc; const float* cnt;
  long long lda, ldb, ldc, sa_b, sb_b, sc_b, sadd_b;
  float alpha;
  int K, k_chunk, tm, tn, batched, mode, aflag, bflag, nblocks;
};
struct GJobs { GJob j[2]; };

__global__ __launch_bounds__(256, 4) void gemm64(GJobs JJ) {
  __shared__ alignas(16) u16 As[2][64 * 64];
  __shared__ alignas(16) u16 Bs[2][64 * 64];

  int b = blockIdx.x;
  GJob J = JJ.j[0];
  if (b >= J.nblocks) { b -= J.nblocks; J = JJ.j[1]; }

  const int tilesper = J.tm * J.tn;
  const int bz = b / tilesper;
  const int rel = b % tilesper;
  const long long m0 = (long long)(rel / J.tn) * 64;
  const long long n0 = (long long)(rel % J.tn) * 64;

  long long aoff = 0, boff = 0, coff = 0, doff = 0, k0 = 0;
  int Kl = J.K;
  if (J.batched) {
    aoff = (long long)bz * J.sa_b;
    boff = (long long)bz * J.sb_b;
    coff = (long long)bz * J.sc_b;
    doff = (long long)bz * J.sadd_b;
  } else {
    k0 = (long long)bz * J.k_chunk;
    Kl = J.k_chunk;
  }

  const int tid = threadIdx.x;
  const int lane = tid & 63, wave = tid >> 6;
  const int wm = (wave & 1) * 32, wn = (wave >> 1) * 32;
  const int fm = lane & 15, fg = lane >> 4;

  auto stage = [&](u16* dst, const void* src, long long ld, long long off,
                   long long rbase, long long t, int isf32) {
    if (!isf32) {
      const u16* gb = (const u16*)src + off;
#pragma unroll
      for (int j = 0; j < 2; ++j) {
        int cc = wave * 2 + j;
        int row = cc * 8 + (lane >> 3);
        int cg = (lane & 7) ^ (row & 7);
        const u16* g = gb + (rbase + row) * ld + t + cg * 8;
        __builtin_amdgcn_global_load_lds((gas_t)(const void*)g,
                                         (las_t)(void*)(dst + cc * 512 + lane * 8),
                                         16, 0, 0);
      }
    } else {
      const float* gb = (const float*)src + off;
#pragma unroll
      for (int p = 0; p < 2; ++p) {
        int idx = p * 256 + tid;
        int row = idx >> 3, cg = idx & 7;
        const float* g = gb + (rbase + row) * ld + t + cg * 8;
        float4 v0 = *(const float4*)g;
        float4 v1 = *(const float4*)(g + 4);
        *(uint4*)&dst[row * 64 + ((cg ^ (row & 7)) * 8)] = pack8(v0, v1);
      }
    }
  };

  f32x4 acc[2][2];
#pragma unroll
  for (int i = 0; i < 2; ++i)
#pragma unroll
    for (int j = 0; j < 2; ++j) acc[i][j] = (f32x4){0.f, 0.f, 0.f, 0.f};

  const int nIter = Kl >> 6;
  stage(As[0], J.A, J.lda, aoff, m0, k0, J.aflag);
  stage(Bs[0], J.Bp, J.ldb, boff, n0, k0, J.bflag);

  for (int i = 0; i < nIter; ++i) {
    __syncthreads();  // drains current buffer's loads
    if (i + 1 < nIter) {
      long long t = k0 + (long long)(i + 1) * 64;
      stage(As[(i + 1) & 1], J.A, J.lda, aoff, m0, t, J.aflag);
      stage(Bs[(i + 1) & 1], J.Bp, J.ldb, boff, n0, t, J.bflag);
    }
    const u16* Ab = As[i & 1];
    const u16* Bb = Bs[i & 1];
#pragma unroll
    for (int kcc = 0; kcc < 8; kcc += 4) {
      bf16x8 af[2], bf[2];
#pragma unroll
      for (int fi = 0; fi < 2; ++fi) {
        int row = wm + fi * 16 + fm;
        af[fi] = *(const bf16x8*)&Ab[row * 64 + (((kcc + fg) ^ (row & 7)) * 8)];
      }
#pragma unroll
      for (int fj = 0; fj < 2; ++fj) {
        int row = wn + fj * 16 + fm;
        bf[fj] = *(const bf16x8*)&Bb[row * 64 + (((kcc + fg) ^ (row & 7)) * 8)];
      }
#pragma unroll
      for (int fi = 0; fi < 2; ++fi)
#pragma unroll
        for (int fj = 0; fj < 2; ++fj)
          acc[fi][fj] = __builtin_amdgcn_mfma_f32_16x16x32_bf16(af[fi], bf[fj], acc[fi][fj], 0, 0, 0);
    }
  }

  float inv = (J.mode == 3) ? 1.0f / (*J.cnt + 1e-6f) : 0.0f;
#pragma unroll
  for (int fi = 0; fi < 2; ++fi) {
#pragma unroll
    for (int r = 0; r < 4; ++r) {
      long long row = m0 + wm + fi * 16 + fg * 4 + r;
#pragma unroll
      for (int fj = 0; fj < 2; ++fj) {
        long long col = n0 + wn + fj * 16 + fm;
        long long idx = row * J.ldc + col;
        float v = acc[fi][fj][r];
        if (J.mode == 0) {
          atomicAdd((float*)J.C + idx, v * J.alpha);
        } else if (J.mode == 1) {
          ((u16*)J.C)[coff + idx] = f2bf(v * J.alpha);
        } else if (J.mode == 2) {
          ((float*)J.C)[coff + idx] = v * J.alpha;
        } else {
          ((float*)J.C)[coff + idx] = J.addsrc[doff + idx] + v * inv;
        }
      }
    }
  }
}

extern "C" void kernel_launch(void* const* d_in, const int* in_sizes, int n_in,
                              void* d_out, int out_size, void* d_ws, size_t ws_size,
                              hipStream_t stream) {
  (void)in_sizes; (void)n_in; (void)out_size; (void)ws_size;
  const float* zq   = (const float*)d_in[0];
  const float* zs   = (const float*)d_in[1];
  const float* zv   = (const float*)d_in[2];
  const float* conf = (const float*)d_in[3];
  const float* Wk   = (const float*)d_in[4];
  const float* Wv   = (const float*)d_in[5];
  const float* Wo   = (const float*)d_in[6];
  const float* mem  = (const float*)d_in[7];

  float* vret = (float*)d_out;                      // (B, D)
  float* newmem = vret + (long long)B_DIM * D_DIM;  // (H, D, D)

  float* count = (float*)d_ws;
  float* Pf = (float*)((char*)d_ws + 256);
  float* Sf = (float*)((char*)d_ws + 256 + 1048576);
  u16* bb   = (u16*)((char*)d_ws + 2097408);
  u16* zsT   = bb;              // 512 x 4096
  u16* zvlT  = bb + 2097152;    // 512 x 4096 (lam-scaled)
  u16* WkT   = bb + 4194304;    // 8192 x 512
  u16* WvT   = bb + 8388608;    // 8192 x 512
  u16* memT  = bb + 12582912;   // 512 x 8192
  u16* WoT   = bb + 16777216;   // 512 x 512
  u16* QT    = bb + 17039360;   // 512 x 512 (Q^T, /16 folded)
  u16* UT    = bb + 17301504;   // 16 x 512 x 512 (U_h^T)
  u16* Wk_bf = bb + 21495808;   // 512 x 8192 row-major

  // D1: transposes + convert + zero(Pf,Sf) + count (no separate memset)
  TJobs T;
  T.j[0] = {zs,   zsT,   nullptr, 4096, 512,  16,  0,     0};
  T.j[1] = {zv,   zvlT,  conf,    4096, 512,  16,  2048,  1};
  T.j[2] = {Wk,   WkT,   nullptr, 512,  8192, 256, 4096,  0};
  T.j[3] = {Wv,   WvT,   nullptr, 512,  8192, 256, 8192,  0};
  T.j[4] = {mem,  memT,  nullptr, 8192, 512,  16,  12288, 0};
  T.j[5] = {Wo,   WoT,   nullptr, 512,  512,  16,  16384, 0};
  T.j[6] = {Wk,   Wk_bf, nullptr, 512,  8192, 0,   16640, 3};   // 2048 blocks
  T.j[7] = {nullptr, Pf, nullptr, 0, 0, 0,    18688, 4};        // 64 blocks
  T.j[8] = {nullptr, Sf, nullptr, 0, 0, 0,    18752, 4};        // 64 blocks
  T.j[9] = {conf, nullptr, nullptr, 0, 0, 0,  18816, 2};        // 1 block
  mega_prep<<<18817, 256, 0, stream>>>(T, count);

  // D2: G1 (Pf = Wk @ M, K=8192, split-K 8) + G4 (Sf = zsT @ zvlT^T, K=4096, split-K 8)
  GJobs D2;
  D2.j[0] = {Wk_bf, memT, Pf, nullptr, nullptr,
             8192, 8192, 512, 0, 0, 0, 0,
             1.0f, 8192, 1024, 8, 8, 0, 0, 0, 0, 512};
  D2.j[1] = {zsT, zvlT, Sf, nullptr, nullptr,
             4096, 4096, 512, 0, 0, 0, 0,
             1.0f, 4096, 512, 8, 8, 0, 0, 0, 0, 512};
  gemm64<<<1024, 256, 0, stream>>>(D2);

  // D3: G5 (UT_h = WvT_h @ Sf^T, batched 16) + G2 (QT = WoT @ Pf^T, /16)
  GJobs D3;
  D3.j[0] = {WvT, Sf, UT, nullptr, nullptr,
             512, 512, 512, 262144, 0, 262144, 0,
             1.0f, 512, 512, 8, 8, 1, 1, 0, 1, 1024};
  D3.j[1] = {WoT, Pf, QT, nullptr, nullptr,
             512, 512, 512, 0, 0, 0, 0,
             1.0f / 16.0f, 512, 512, 8, 8, 0, 1, 0, 1, 64};
  gemm64<<<1088, 256, 0, stream>>>(D3);

  // D4: G6 (newmem = mem + WkT_h @ UT_h^T / count, batched 16) + G3 (vret = zq @ QT^T)
  GJobs D4;
  D4.j[0] = {WkT, UT, newmem, mem, count,
             512, 512, 512, 262144, 262144, 262144, 262144,
             1.0f, 512, 512, 8, 8, 1, 3, 0, 0, 1024};
  D4.j[1] = {zq, QT, vret, nullptr, nullptr,
             512, 512, 512, 0, 0, 0, 0,
             1.0f, 512, 512, 64, 8, 0, 2, 1, 0, 512};
  gemm64<<<1536, 256, 0, stream>>>(D4);
}